// Round 1
// baseline (1004.070 us; speedup 1.0000x reference)
//
#include <hip/hip_runtime.h>
#include <math.h>

#define BB  4
#define CC  256
#define DQ  32
#define NN  4096
#define TI  32
#define TJ  32
#define CH  8

// ---------------- projections: q,k,v = W @ x + b ----------------
// grid: BB * (320/CH) * (NN/256), block 256.
__global__ __launch_bounds__(256) void proj_kernel(
    const float* __restrict__ x,
    const float* __restrict__ wq, const float* __restrict__ bq,
    const float* __restrict__ wk, const float* __restrict__ bk,
    const float* __restrict__ wv, const float* __restrict__ bv,
    float* __restrict__ q, float* __restrict__ k, float* __restrict__ v)
{
    const int NT = NN / 256;
    int ntile = blockIdx.x % NT;
    int cg    = (blockIdx.x / NT) % (320 / CH);
    int b     = blockIdx.x / (NT * (320 / CH));
    int n     = ntile * 256 + threadIdx.x;
    int ch0   = cg * CH;

    const float* w; const float* bias; float* o; int row0;
    if (ch0 < 32)      { w = wq; bias = bq; o = q + (size_t)b * DQ * NN; row0 = ch0; }
    else if (ch0 < 64) { w = wk; bias = bk; o = k + (size_t)b * DQ * NN; row0 = ch0 - 32; }
    else               { w = wv; bias = bv; o = v + (size_t)b * CC * NN; row0 = ch0 - 64; }

    float acc[CH];
#pragma unroll
    for (int t = 0; t < CH; t++) acc[t] = bias[row0 + t];

    const float* xb = x + (size_t)b * CC * NN + n;
#pragma unroll 4
    for (int c = 0; c < CC; c++) {
        float xv = xb[(size_t)c * NN];
#pragma unroll
        for (int t = 0; t < CH; t++)
            acc[t] = fmaf(w[(row0 + t) * CC + c], xv, acc[t]);
    }
#pragma unroll
    for (int t = 0; t < CH; t++) o[(size_t)(row0 + t) * NN + n] = acc[t];
}

// ---------------- fused attention ----------------
// One block per (b, 32-token i-tile). No max-subtraction: logits bounded ~|34|,
// exp() safe in fp32 (overflow at 88). Unnormalized accumulate + final divide.
__global__ __launch_bounds__(256) void attn_kernel(
    const float* __restrict__ q, const float* __restrict__ kg,
    const float* __restrict__ vg, const float* __restrict__ x,
    const float* __restrict__ gamma, float* __restrict__ out)
{
    __shared__ float qt[TI][DQ];      // 4 KB
    __shared__ float kt[TJ][36];      // [j][d], pad 36 for aligned b128, bank-spread
    __shared__ float vt[CC][TJ];      // quad-XOR swizzled: logical quad jq at (jq ^ (c&7))
    __shared__ float pt[TI][TJ];      // exp(logits)
    __shared__ float dred[TI][TJ];    // denom partials
    __shared__ float dsh[TI];

    const int tid = threadIdx.x;
    const int b  = blockIdx.x / (NN / TI);
    const int i0 = (blockIdx.x % (NN / TI)) * TI;

    // load q tile [i][d]
    for (int idx = tid; idx < TI * DQ; idx += 256) {
        int i = idx & 31, d = idx >> 5;
        qt[i][d] = q[((size_t)b * DQ + d) * NN + i0 + i];
    }

    const int jl = tid & 31;          // logit lane j, rows {jg, jg+8, +16, +24}
    const int jg = tid >> 5;
    const int ci = tid & 31;          // PV: c = ci + 32*kk
    const int ip = (tid >> 5) << 2;   // PV rows ip..ip+3

    float acc[4][8];
#pragma unroll
    for (int m = 0; m < 4; m++)
#pragma unroll
        for (int kk = 0; kk < 8; kk++) acc[m][kk] = 0.f;
    float dpart[4] = {0.f, 0.f, 0.f, 0.f};

    const float* kb = kg + (size_t)b * DQ * NN;
    const float* vb = vg + (size_t)b * CC * NN;

    for (int jt = 0; jt < NN / TJ; jt++) {
        const int j0 = jt * TJ;
        __syncthreads();   // prior-iter LDS reads done before overwrite
        // K tile transposed [j][d]
        for (int idx = tid; idx < DQ * TJ; idx += 256) {
            int j = idx & 31, d = idx >> 5;
            kt[j][d] = kb[(size_t)d * NN + j0 + j];
        }
        // V tile, float4 loads, XOR-swizzle quads
        for (int idx = tid; idx < CC * TJ / 4; idx += 256) {
            int c = idx >> 3, jq = idx & 7;
            float4 vv = *(const float4*)&vb[(size_t)c * NN + j0 + (jq << 2)];
            *(float4*)&vt[c][(jq ^ (c & 7)) << 2] = vv;
        }
        __syncthreads();

        // logits + exp (4 rows per thread)
#pragma unroll
        for (int m = 0; m < 4; m++) {
            int i = jg + 8 * m;
            float dot = 0.f;
#pragma unroll
            for (int dc = 0; dc < DQ / 4; dc++) {
                float4 q4 = *(const float4*)&qt[i][dc << 2];
                float4 k4 = *(const float4*)&kt[jl][dc << 2];
                dot = fmaf(q4.x, k4.x, dot);
                dot = fmaf(q4.y, k4.y, dot);
                dot = fmaf(q4.z, k4.z, dot);
                dot = fmaf(q4.w, k4.w, dot);
            }
            float p = __expf(dot);
            pt[i][jl] = p;
            dpart[m] += p;
        }
        __syncthreads();

        // PV: thread tile 4i x 8c
#pragma unroll
        for (int jc = 0; jc < TJ / 4; jc++) {
            float4 p4[4];
#pragma unroll
            for (int m = 0; m < 4; m++)
                p4[m] = *(const float4*)&pt[ip + m][jc << 2];
#pragma unroll
            for (int kk = 0; kk < 8; kk++) {
                int c = ci + 32 * kk;
                float4 v4 = *(const float4*)&vt[c][((jc ^ (ci & 7)) << 2)];
#pragma unroll
                for (int m = 0; m < 4; m++) {
                    acc[m][kk] = fmaf(p4[m].x, v4.x, acc[m][kk]);
                    acc[m][kk] = fmaf(p4[m].y, v4.y, acc[m][kk]);
                    acc[m][kk] = fmaf(p4[m].z, v4.z, acc[m][kk]);
                    acc[m][kk] = fmaf(p4[m].w, v4.w, acc[m][kk]);
                }
            }
        }
    }

    // denominator reduce
    __syncthreads();
#pragma unroll
    for (int m = 0; m < 4; m++) dred[jg + 8 * m][jl] = dpart[m];
    __syncthreads();
    if (tid < TI) {
        float s = 0.f;
        for (int j = 0; j < TJ; j++) s += dred[tid][j];
        dsh[tid] = s;
    }
    __syncthreads();

    // epilogue: normalize, scale by gamma, stage transposed in vt, add x, write
    const float g = gamma[0];
#pragma unroll
    for (int m = 0; m < 4; m++) {
        int i = ip + m;
        float sc = g / dsh[i];
#pragma unroll
        for (int kk = 0; kk < 8; kk++) {
            int c = ci + 32 * kk;
            vt[c][((((i >> 2) ^ (c & 7)) << 2) | (i & 3))] = acc[m][kk] * sc;
        }
    }
    __syncthreads();
    const float* xb = x + (size_t)b * CC * NN + i0;
    float* ob = out + (size_t)b * CC * NN + i0;
    for (int idx = tid; idx < CC * TI; idx += 256) {
        int c = idx >> 5, i = idx & 31;
        float val = vt[c][((((i >> 2) ^ (c & 7)) << 2) | (i & 3))];
        ob[(size_t)c * NN + i] = val + xb[(size_t)c * NN + i];
    }
}

extern "C" void kernel_launch(void* const* d_in, const int* in_sizes, int n_in,
                              void* d_out, int out_size, void* d_ws, size_t ws_size,
                              hipStream_t stream) {
    const float* x     = (const float*)d_in[0];
    const float* wq    = (const float*)d_in[1];
    const float* bq    = (const float*)d_in[2];
    const float* wk    = (const float*)d_in[3];
    const float* bk    = (const float*)d_in[4];
    const float* wv    = (const float*)d_in[5];
    const float* bv    = (const float*)d_in[6];
    const float* gamma = (const float*)d_in[7];
    float* out = (float*)d_out;

    float* ws = (float*)d_ws;
    float* q = ws;                                   // B*DQ*N floats (2 MB)
    float* k = ws + (size_t)BB * DQ * NN;            // 2 MB
    float* v = ws + (size_t)2 * BB * DQ * NN;        // B*C*N floats (16 MB)

    proj_kernel<<<dim3(BB * (320 / CH) * (NN / 256)), 256, 0, stream>>>(
        x, wq, bq, wk, bk, wv, bv, q, k, v);
    attn_kernel<<<dim3(BB * (NN / TI)), 256, 0, stream>>>(
        q, k, v, x, gamma, out);
}

// Round 2
// 229.241 us; speedup vs baseline: 4.3800x; 4.3800x over previous
//
#include <hip/hip_runtime.h>

#define BB   4
#define CC   256
#define DQ   32
#define NSEQ 4096
#define TI   64
#define TJ   64

typedef __attribute__((ext_vector_type(8)))  short          bhalf8;   // 8 bf16 = 4 VGPRs
typedef __attribute__((ext_vector_type(16))) float          f32x16;   // 32x32 C/D
typedef __attribute__((ext_vector_type(8)))  unsigned short ushort8;

__device__ __forceinline__ unsigned short f2bf(float f) {
    unsigned u = __float_as_uint(f);
    u += 0x7FFFu + ((u >> 16) & 1u);   // RNE
    return (unsigned short)(u >> 16);
}

// ---------------- projections: fp32 compute, bf16 outputs ----------------
// q_t,k_t: [B][N][32] (token-major, frag-shaped).  v_t: [B][C][N].
__global__ __launch_bounds__(256) void proj_kernel(
    const float* __restrict__ x,
    const float* __restrict__ wq, const float* __restrict__ bq,
    const float* __restrict__ wk, const float* __restrict__ bk,
    const float* __restrict__ wv, const float* __restrict__ bv,
    unsigned short* __restrict__ qt, unsigned short* __restrict__ kt,
    unsigned short* __restrict__ vt)
{
    const int NTL = NSEQ / 256;                 // 16 n-tiles
    int ntile = blockIdx.x % NTL;
    int cg    = (blockIdx.x / NTL) % 40;        // 320 fused rows / 8
    int b     = blockIdx.x / (NTL * 40);
    int n     = ntile * 256 + threadIdx.x;
    int ch0   = cg * 8;

    const float* w; const float* bias; int row0; int mode;
    if (ch0 < 32)      { w = wq; bias = bq; row0 = ch0;      mode = 0; }
    else if (ch0 < 64) { w = wk; bias = bk; row0 = ch0 - 32; mode = 1; }
    else               { w = wv; bias = bv; row0 = ch0 - 64; mode = 2; }

    float acc[8];
#pragma unroll
    for (int t = 0; t < 8; t++) acc[t] = bias[row0 + t];

    const float* xb = x + (size_t)b * CC * NSEQ + n;
#pragma unroll 4
    for (int c = 0; c < CC; c++) {
        float xv = xb[(size_t)c * NSEQ];
#pragma unroll
        for (int t = 0; t < 8; t++)
            acc[t] = fmaf(w[(row0 + t) * CC + c], xv, acc[t]);
    }

    if (mode == 2) {
#pragma unroll
        for (int t = 0; t < 8; t++)
            vt[((size_t)b * CC + row0 + t) * NSEQ + n] = f2bf(acc[t]);
    } else {
        ushort8 o;
#pragma unroll
        for (int t = 0; t < 8; t++) o[t] = f2bf(acc[t]);
        unsigned short* dst = (mode == 0 ? qt : kt) + ((size_t)b * NSEQ + n) * DQ + row0;
        *(ushort8*)dst = o;
    }
}

// ---------------- fused attention, bf16 MFMA 32x32x16 ----------------
// Block = (b, 64-row i-tile); 4 waves. K/V B-frags straight from global (L2).
// P (=exp scores) round-trips LDS with XOR-swizzled 16B granules.
// Layouts: A[m=l&31][k=(l>>5)*8+e], B[k=(l>>5)*8+e][n=l&31],
//          C/D col=l&31, row=(reg&3)+8*(reg>>2)+4*(l>>5)  [verified m74/m101].
__global__ __launch_bounds__(256, 1) void attn_kernel(
    const unsigned short* __restrict__ qg, const unsigned short* __restrict__ kg,
    const unsigned short* __restrict__ vg, const float* __restrict__ x,
    const float* __restrict__ gamma, float* __restrict__ out)
{
    __shared__ unsigned short pt[TI * TJ];  // 8 KB, swizzled granules
    __shared__ float dsum[2][TI];
    __shared__ float dinv[TI];

    const int tid = threadIdx.x;
    const int w   = tid >> 6;
    const int l   = tid & 63;
    const int l31 = l & 31;
    const int l5  = l >> 5;
    const int b   = blockIdx.x / (NSEQ / TI);
    const int i0  = (blockIdx.x % (NSEQ / TI)) * TI;
    const int ibs = w >> 1;        // S-phase i-block
    const int jb  = w & 1;         // S-phase j-block

    // loop-invariant Q A-frags (rows 32*ibs.., K-dim = 32 in two halves)
    const unsigned short* qb = qg + ((size_t)b * NSEQ + i0) * DQ;
    bhalf8 qa[2];
#pragma unroll
    for (int kh = 0; kh < 2; kh++)
        qa[kh] = *(const bhalf8*)(qb + (32 * ibs + l31) * DQ + kh * 16 + l5 * 8);

    f32x16 acc[2][2] = {};         // [ib][cbx] out tiles: rows 32ib.., cols 64w+32cbx..
    float dpart[16] = {};

    const unsigned short* kb = kg + (size_t)b * NSEQ * DQ;
    const unsigned short* vb = vg + (size_t)b * CC * NSEQ;

    for (int jt = 0; jt < NSEQ / TJ; jt++) {
        const int j0 = jt * TJ;

        bhalf8 kf[2];
#pragma unroll
        for (int kh = 0; kh < 2; kh++)
            kf[kh] = *(const bhalf8*)(kb + (size_t)(j0 + 32 * jb + l31) * DQ + kh * 16 + l5 * 8);
        bhalf8 vf[2][4];
#pragma unroll
        for (int cbx = 0; cbx < 2; cbx++)
#pragma unroll
            for (int kh = 0; kh < 4; kh++)
                vf[cbx][kh] = *(const bhalf8*)(vb + (size_t)(64 * w + 32 * cbx + l31) * NSEQ
                                               + j0 + kh * 16 + l5 * 8);

        // S = Q.K^T  (one 32x32 tile per wave, K=32 in two MFMAs)
        f32x16 s = {};
        s = __builtin_amdgcn_mfma_f32_32x32x16_bf16(qa[0], kf[0], s, 0, 0, 0);
        s = __builtin_amdgcn_mfma_f32_32x32x16_bf16(qa[1], kf[1], s, 0, 0, 0);

        float pe[16];
#pragma unroll
        for (int r = 0; r < 16; r++) {
            float p = __expf(s[r]);          // logits bounded ~|34|: no max-sub needed
            pe[r] = p;
            dpart[r] += p;
        }

        __syncthreads();                     // prior-iter pt reads complete
#pragma unroll
        for (int r = 0; r < 16; r++) {
            int il = 32 * ibs + (r & 3) + 8 * (r >> 2) + 4 * l5;
            int jl = 32 * jb + l31;
            pt[il * 64 + (((jl >> 3) ^ (il & 7)) << 3) + (jl & 7)] = f2bf(pe[r]);
        }
        __syncthreads();                     // pt visible

        // P A-frags back from LDS (conflict-free b128 via swizzle)
        bhalf8 pa[2][4];
#pragma unroll
        for (int ib = 0; ib < 2; ib++)
#pragma unroll
            for (int kh = 0; kh < 4; kh++) {
                int il = 32 * ib + l31;
                pa[ib][kh] = *(const bhalf8*)&pt[il * 64 + (((2 * kh + l5) ^ (il & 7)) << 3)];
            }

#pragma unroll
        for (int ib = 0; ib < 2; ib++)
#pragma unroll
            for (int cbx = 0; cbx < 2; cbx++)
#pragma unroll
                for (int kh = 0; kh < 4; kh++)
                    acc[ib][cbx] = __builtin_amdgcn_mfma_f32_32x32x16_bf16(
                        pa[ib][kh], vf[cbx][kh], acc[ib][cbx], 0, 0, 0);
    }

    // denominator: reduce dpart over the 32 j-lanes, combine the two jb waves
#pragma unroll
    for (int m = 16; m >= 1; m >>= 1)
#pragma unroll
        for (int r = 0; r < 16; r++)
            dpart[r] += __shfl_xor(dpart[r], m, 64);
    if (l31 == 0) {
#pragma unroll
        for (int r = 0; r < 16; r++) {
            int il = 32 * ibs + (r & 3) + 8 * (r >> 2) + 4 * l5;
            dsum[jb][il] = dpart[r];
        }
    }
    __syncthreads();
    if (tid < TI) dinv[tid] = gamma[0] / (dsum[0][tid] + dsum[1][tid]);
    __syncthreads();

    // epilogue: normalize*gamma + x, float4 stores (rows are n-consecutive)
#pragma unroll
    for (int ib = 0; ib < 2; ib++)
#pragma unroll
        for (int cbx = 0; cbx < 2; cbx++) {
            int c = 64 * w + 32 * cbx + l31;
            const size_t rowoff = ((size_t)b * CC + c) * NSEQ + i0;
#pragma unroll
            for (int rg = 0; rg < 4; rg++) {
                int ibase = 32 * ib + 8 * rg + 4 * l5;
                float4 xr = *(const float4*)(x + rowoff + ibase);
                float4 o;
                o.x = acc[ib][cbx][4 * rg + 0] * dinv[ibase + 0] + xr.x;
                o.y = acc[ib][cbx][4 * rg + 1] * dinv[ibase + 1] + xr.y;
                o.z = acc[ib][cbx][4 * rg + 2] * dinv[ibase + 2] + xr.z;
                o.w = acc[ib][cbx][4 * rg + 3] * dinv[ibase + 3] + xr.w;
                *(float4*)(out + rowoff + ibase) = o;
            }
        }
}

extern "C" void kernel_launch(void* const* d_in, const int* in_sizes, int n_in,
                              void* d_out, int out_size, void* d_ws, size_t ws_size,
                              hipStream_t stream) {
    const float* x     = (const float*)d_in[0];
    const float* wq    = (const float*)d_in[1];
    const float* bq    = (const float*)d_in[2];
    const float* wk    = (const float*)d_in[3];
    const float* bk    = (const float*)d_in[4];
    const float* wv    = (const float*)d_in[5];
    const float* bv    = (const float*)d_in[6];
    const float* gamma = (const float*)d_in[7];
    float* out = (float*)d_out;

    unsigned short* ws = (unsigned short*)d_ws;
    unsigned short* qt = ws;                                    // 1 MB
    unsigned short* kt = ws + (size_t)BB * NSEQ * DQ;           // 1 MB
    unsigned short* vt = ws + (size_t)2 * BB * NSEQ * DQ;       // 8 MB

    proj_kernel<<<dim3(BB * 40 * (NSEQ / 256)), 256, 0, stream>>>(
        x, wq, bq, wk, bk, wv, bv, qt, kt, vt);
    attn_kernel<<<dim3(BB * (NSEQ / TI)), 256, 0, stream>>>(
        qt, kt, vt, x, gamma, out);
}

// Round 3
// 170.734 us; speedup vs baseline: 5.8809x; 1.3427x over previous
//
#include <hip/hip_runtime.h>

#define BB   4
#define CCH  256
#define DQ   32
#define NS   4096
#define TI   64
#define TJ   128

typedef __attribute__((ext_vector_type(8)))  short          bhalf8;   // 8 bf16 = 4 VGPRs
typedef __attribute__((ext_vector_type(16))) float          f32x16;   // 32x32 C/D
typedef __attribute__((ext_vector_type(8)))  unsigned short u16x8;

__device__ __forceinline__ unsigned short f2bf(float f) {
    unsigned u = __float_as_uint(f);
    u += 0x7FFFu + ((u >> 16) & 1u);   // RNE
    return (unsigned short)(u >> 16);
}

__device__ __forceinline__ void async_copy16(unsigned short* lds, const unsigned short* g) {
    __builtin_amdgcn_global_load_lds(
        (const __attribute__((address_space(1))) unsigned int*)g,
        (__attribute__((address_space(3))) unsigned int*)lds, 16, 0, 0);
}

// ---------------- cast x -> xT bf16 [B][N][C] (transpose for proj B-frags) ----
// grid BB*64, block 256. Wave w handles c-range [64w,64w+64), lanes = 64 tokens.
__global__ __launch_bounds__(256) void cast_x_kernel(
    const float* __restrict__ x, unsigned short* __restrict__ xT)
{
    int b  = blockIdx.x >> 6;
    int n  = ((blockIdx.x & 63) << 6) + (threadIdx.x & 63);
    int cq = threadIdx.x >> 6;
    unsigned short* xo = xT + ((size_t)b * NS + n) * CCH;
#pragma unroll
    for (int j8 = 0; j8 < 8; j8++) {
        int cb = cq * 64 + j8 * 8;
        u16x8 o;
#pragma unroll
        for (int j = 0; j < 8; j++)
            o[j] = f2bf(x[((size_t)b * CCH + cb + j) * NS + n]);
        *(u16x8*)(xo + cb) = o;
    }
}

// ---------------- cast W -> Wc bf16 [320][256] (rows: 32 q, 32 k, 256 v) -----
__global__ __launch_bounds__(256) void cast_w_kernel(
    const float* __restrict__ wq, const float* __restrict__ wk,
    const float* __restrict__ wv, unsigned short* __restrict__ Wc)
{
    int idx = blockIdx.x * 256 + threadIdx.x;   // grid 320 -> 81920
    int m = idx >> 8, c = idx & 255;
    float v = (m < 32) ? wq[m * 256 + c]
            : (m < 64) ? wk[(m - 32) * 256 + c]
                       : wv[(m - 64) * 256 + c];
    Wc[idx] = f2bf(v);
}

// ---------------- proj: MFMA GEMM  O[320][n] = Wc @ xT^T + bias --------------
// grid 256 = b(4) x nb(32, 128 tokens) x ms(2, 160 rows). 4 waves; wave = 32 tokens.
__global__ __launch_bounds__(256) void proj_kernel(
    const unsigned short* __restrict__ xT, const unsigned short* __restrict__ Wc,
    const float* __restrict__ bq, const float* __restrict__ bk,
    const float* __restrict__ bv,
    unsigned short* __restrict__ qt, unsigned short* __restrict__ kt,
    unsigned short* __restrict__ vt)
{
    const int ms = blockIdx.x & 1;
    const int nb = (blockIdx.x >> 1) & 31;
    const int b  = blockIdx.x >> 6;
    const int w = threadIdx.x >> 6, l = threadIdx.x & 63;
    const int l31 = l & 31, l5 = l >> 5;
    const int n0w = nb * 128 + w * 32;

    const unsigned short* bp = xT + ((size_t)b * NS + n0w + l31) * CCH + l5 * 8;
    const unsigned short* ap = Wc + (size_t)(ms * 160 + l31) * CCH + l5 * 8;

    f32x16 acc[5] = {};
    for (int kh = 0; kh < 16; kh++) {
        bhalf8 bf = *(const bhalf8*)(bp + kh * 16);
#pragma unroll
        for (int it = 0; it < 5; it++) {
            bhalf8 af = *(const bhalf8*)(ap + (size_t)it * 32 * CCH + kh * 16);
            acc[it] = __builtin_amdgcn_mfma_f32_32x32x16_bf16(af, bf, acc[it], 0, 0, 0);
        }
    }

    // epilogue: C/D row = (r&3)+8*(r>>2)+4*l5, col = token = l31
#pragma unroll
    for (int it = 0; it < 5; it++) {
        int r0 = ms * 160 + it * 32;
        if (r0 < 64) {
            unsigned short* dst = (r0 == 0 ? qt : kt) + ((size_t)b * NS + n0w + l31) * DQ;
            const float* bias = (r0 == 0 ? bq : bk);
#pragma unroll
            for (int g = 0; g < 4; g++) {
                int m0 = g * 8 + l5 * 4;
                float4 bs = *(const float4*)(bias + m0);
                ushort4 o;
                o.x = f2bf(acc[it][4 * g + 0] + bs.x);
                o.y = f2bf(acc[it][4 * g + 1] + bs.y);
                o.z = f2bf(acc[it][4 * g + 2] + bs.z);
                o.w = f2bf(acc[it][4 * g + 3] + bs.w);
                *(ushort4*)(dst + m0) = o;
            }
        } else {
            int c0 = r0 - 64;
#pragma unroll
            for (int g = 0; g < 4; g++) {
                int m0 = g * 8 + l5 * 4;
                float4 bs = *(const float4*)(bv + c0 + m0);
                const float* bse = (const float*)&bs;
#pragma unroll
                for (int e = 0; e < 4; e++)
                    vt[((size_t)b * CCH + c0 + m0 + e) * NS + n0w + l31] =
                        f2bf(acc[it][4 * g + e] + bse[e]);
            }
        }
    }
}

// ---------------- fused attention: 8 waves, TI=64, TJ=128 --------------------
// V staged global->LDS (async, dbuf, XOR-swizzled 16B granules); P via LDS.
// No max-subtraction: logits bounded ~|34| << 88 (fp32 exp overflow).
__global__ __launch_bounds__(512, 2) void attn_kernel(
    const unsigned short* __restrict__ qg, const unsigned short* __restrict__ kg,
    const unsigned short* __restrict__ vg, const float* __restrict__ x,
    const float* __restrict__ gamma, float* __restrict__ out)
{
    __shared__ unsigned short vbuf[2][CCH][TJ];   // 128 KB
    __shared__ unsigned short pt[TI][TJ];         // 16 KB
    __shared__ float dsum[4][TI];
    __shared__ float dinv[TI];

    const int tid = threadIdx.x;
    const int w = tid >> 6, l = tid & 63;
    const int l31 = l & 31, l5 = l >> 5;
    const int b  = blockIdx.x >> 6;
    const int i0 = (blockIdx.x & 63) * TI;
    const int ibs = w >> 2, jb = w & 3;           // S-phase tile of this wave

    const unsigned short* qb = qg + ((size_t)b * NS + i0) * DQ;
    const unsigned short* kb = kg + (size_t)b * NS * DQ;
    const unsigned short* vb = vg + (size_t)b * CCH * NS;

    // V staging: lane -> row c = cbase + (l>>4), phys granule l&15,
    // logical granule g = (l&15) ^ (c&15); 8 insts/wave cover rows 32w..32w+31.
    const int vc = (w * 32) + (l >> 4);           // advanced by t*4 per inst
    const int vg_log = (l & 15) ^ (vc & 15);
    const unsigned short* vsrc0 = vb + (size_t)vc * NS + vg_log * 8;

    // loop-invariant Q A-frags
    bhalf8 qa[2];
#pragma unroll
    for (int kh = 0; kh < 2; kh++)
        qa[kh] = *(const bhalf8*)(qb + (size_t)(32 * ibs + l31) * DQ + kh * 16 + l5 * 8);

    f32x16 acc[2] = {};
    float dpart[16] = {};

    // prologue: V tile 0 + K frags tile 0
#pragma unroll
    for (int t = 0; t < 8; t++)
        async_copy16(&vbuf[0][w * 32 + t * 4][0], vsrc0 + (size_t)t * 4 * NS);
    bhalf8 kf[2], kfn[2];
#pragma unroll
    for (int kh = 0; kh < 2; kh++)
        kf[kh] = *(const bhalf8*)(kb + (size_t)(32 * jb + l31) * DQ + kh * 16 + l5 * 8);

    for (int jt = 0; jt < NS / TJ; jt++) {
        const int buf = jt & 1;

        // S = Q.K^T (32x32 per wave)
        f32x16 s = {};
        s = __builtin_amdgcn_mfma_f32_32x32x16_bf16(qa[0], kf[0], s, 0, 0, 0);
        s = __builtin_amdgcn_mfma_f32_32x32x16_bf16(qa[1], kf[1], s, 0, 0, 0);

        // exp + P-write (swizzled: phys = (jl>>3) ^ (il&15))
#pragma unroll
        for (int r = 0; r < 16; r++) {
            float p = __expf(s[r]);
            dpart[r] += p;
            int il = 32 * ibs + (r & 3) + 8 * (r >> 2) + 4 * l5;
            int jl = 32 * jb + l31;
            pt[il][(((jl >> 3) ^ (il & 15)) << 3) + (jl & 7)] = f2bf(p);
        }
        __syncthreads();   // B1: P visible (drains V tile for this jt too)

        // prefetch next V tile + next K frags (overlaps PV phase, drained at B2)
        if (jt + 1 < NS / TJ) {
            const unsigned short* vsrc = vsrc0 + (size_t)(jt + 1) * TJ;
#pragma unroll
            for (int t = 0; t < 8; t++)
                async_copy16(&vbuf[buf ^ 1][w * 32 + t * 4][0], vsrc + (size_t)t * 4 * NS);
#pragma unroll
            for (int kh = 0; kh < 2; kh++)
                kfn[kh] = *(const bhalf8*)(kb + (size_t)((jt + 1) * TJ + 32 * jb + l31) * DQ
                                           + kh * 16 + l5 * 8);
        }

        // V B-frags from LDS: wave's out cols c = 32w + l31
        const int cv2 = 32 * w + l31;
        bhalf8 vf[8];
#pragma unroll
        for (int kh = 0; kh < 8; kh++)
            vf[kh] = *(const bhalf8*)&vbuf[buf][cv2][(((2 * kh + l5) ^ (cv2 & 15)) << 3)];

        // P A-frags + PV MFMAs
#pragma unroll
        for (int ib = 0; ib < 2; ib++) {
            const int il = 32 * ib + l31;
#pragma unroll
            for (int kh = 0; kh < 8; kh++) {
                bhalf8 pa = *(const bhalf8*)&pt[il][(((2 * kh + l5) ^ (il & 15)) << 3)];
                acc[ib] = __builtin_amdgcn_mfma_f32_32x32x16_bf16(pa, vf[kh], acc[ib], 0, 0, 0);
            }
        }

        if (jt + 1 < NS / TJ) { kf[0] = kfn[0]; kf[1] = kfn[1]; }
        __syncthreads();   // B2: P reads done; next V tile + kfn drained
    }

    // denominator: reduce over 32 j-lanes (l31), combine 4 jb waves via LDS
#pragma unroll
    for (int m = 16; m >= 1; m >>= 1)
#pragma unroll
        for (int r = 0; r < 16; r++)
            dpart[r] += __shfl_xor(dpart[r], m, 64);
    if (l31 == 0) {
#pragma unroll
        for (int r = 0; r < 16; r++) {
            int il = 32 * ibs + (r & 3) + 8 * (r >> 2) + 4 * l5;
            dsum[jb][il] = dpart[r];
        }
    }
    __syncthreads();
    if (tid < TI)
        dinv[tid] = gamma[0] / (dsum[0][tid] + dsum[1][tid] + dsum[2][tid] + dsum[3][tid]);
    __syncthreads();

    // epilogue: stage normalized out-tile in LDS (swizzled), then coalesced
    // read-add-x-store (8 lines/inst instead of 64-line gathers).
    float* otile = (float*)&vbuf[0][0][0];        // 256 x 64 fp32 = 64 KB
    const int c = 32 * w + l31;
#pragma unroll
    for (int ib = 0; ib < 2; ib++)
#pragma unroll
        for (int rg = 0; rg < 4; rg++) {
            int ibase = 32 * ib + 8 * rg + 4 * l5;
            int phys = ((ibase >> 2) ^ (c & 15));
            float4 ov;
            ov.x = acc[ib][4 * rg + 0] * dinv[ibase + 0];
            ov.y = acc[ib][4 * rg + 1] * dinv[ibase + 1];
            ov.z = acc[ib][4 * rg + 2] * dinv[ibase + 2];
            ov.w = acc[ib][4 * rg + 3] * dinv[ibase + 3];
            *(float4*)(otile + c * 64 + phys * 4) = ov;
        }
    __syncthreads();
#pragma unroll
    for (int ri = 0; ri < 8; ri++) {
        int idx = ri * 512 + tid;
        int cc = idx >> 4, gi = idx & 15;
        float4 vo = *(const float4*)(otile + cc * 64 + ((gi ^ (cc & 15)) << 2));
        const size_t go = ((size_t)b * CCH + cc) * NS + i0 + gi * 4;
        float4 xr = *(const float4*)(x + go);
        vo.x += xr.x; vo.y += xr.y; vo.z += xr.z; vo.w += xr.w;
        *(float4*)(out + go) = vo;
    }
}

extern "C" void kernel_launch(void* const* d_in, const int* in_sizes, int n_in,
                              void* d_out, int out_size, void* d_ws, size_t ws_size,
                              hipStream_t stream) {
    const float* x     = (const float*)d_in[0];
    const float* wq    = (const float*)d_in[1];
    const float* bq    = (const float*)d_in[2];
    const float* wk    = (const float*)d_in[3];
    const float* bk    = (const float*)d_in[4];
    const float* wv    = (const float*)d_in[5];
    const float* bv    = (const float*)d_in[6];
    const float* gamma = (const float*)d_in[7];
    float* out = (float*)d_out;

    unsigned short* ws = (unsigned short*)d_ws;
    unsigned short* xT = ws;                         // 4*4096*256 = 8 MB
    unsigned short* Wc = xT + (size_t)BB * NS * CCH; // 160 KB
    unsigned short* qt = Wc + 320 * 256;             // 1 MB
    unsigned short* kt = qt + (size_t)BB * NS * DQ;  // 1 MB
    unsigned short* vt = kt + (size_t)BB * NS * DQ;  // 8 MB

    cast_x_kernel<<<dim3(BB * 64), 256, 0, stream>>>(x, xT);
    cast_w_kernel<<<dim3(320), 256, 0, stream>>>(wq, wk, wv, Wc);
    proj_kernel<<<dim3(256), 256, 0, stream>>>(xT, Wc, bq, bk, bv, qt, kt, vt);
    attn_kernel<<<dim3(BB * (NS / TI)), 512, 0, stream>>>(qt, kt, vt, x, gamma, out);
}

// Round 5
// 162.533 us; speedup vs baseline: 6.1776x; 1.0505x over previous
//
#include <hip/hip_runtime.h>

#define BB   4
#define CCH  256
#define DQ   32
#define NS   4096
#define TI   64
#define TJ   128

typedef __attribute__((ext_vector_type(8)))  short          bhalf8;   // 8 bf16 = 4 VGPRs
typedef __attribute__((ext_vector_type(16))) float          f32x16;   // 32x32 C/D
typedef __attribute__((ext_vector_type(8)))  unsigned short u16x8;

__device__ __forceinline__ unsigned short f2bf(float f) {
    unsigned u = __float_as_uint(f);
    u += 0x7FFFu + ((u >> 16) & 1u);   // RNE
    return (unsigned short)(u >> 16);
}

__device__ __forceinline__ void async_copy16(unsigned short* lds, const unsigned short* g) {
    __builtin_amdgcn_global_load_lds(
        (const __attribute__((address_space(1))) unsigned int*)g,
        (__attribute__((address_space(3))) unsigned int*)lds, 16, 0, 0);
}

// ============ fused projection: casts + GEMM, all staged via LDS =============
// grid 256 = b(4) x nt(32: 128 tokens) x ms(2: 160 of 320 fused rows).
// LDS: W-slice bf16 swizzled (80 KB) + x-slab bf16 [c][n] (64 KB). No global
// gathers: all global reads coalesced; frag reads via LDS.
__global__ __launch_bounds__(256) void proj_kernel(
    const float* __restrict__ x,
    const float* __restrict__ wq, const float* __restrict__ bq,
    const float* __restrict__ wk, const float* __restrict__ bk,
    const float* __restrict__ wv, const float* __restrict__ bv,
    unsigned short* __restrict__ qt, unsigned short* __restrict__ kt,
    unsigned short* __restrict__ vt)
{
    __shared__ unsigned short wl[160 * 256];   // granule-swizzled: g^(r&31)
    __shared__ unsigned short xl[256 * 128];   // [c][n], n within tile

    const int tid = threadIdx.x;
    const int ms  = blockIdx.x & 1;
    const int nt  = (blockIdx.x >> 1) & 31;
    const int b   = blockIdx.x >> 6;           // grid 256 -> b in [0,4)
    const int n0  = nt * 128;

    // stage W rows [ms*160, +160) as bf16, swizzled 16B granules
    for (int i = tid; i < 160 * 32; i += 256) {
        int r = i >> 5, g = i & 31;
        int gr = ms * 160 + r;
        const float* wsrc = gr < 32 ? wq + gr * 256
                          : gr < 64 ? wk + (gr - 32) * 256
                                    : wv + (gr - 64) * 256;
        float4 a = *(const float4*)(wsrc + g * 8);
        float4 c = *(const float4*)(wsrc + g * 8 + 4);
        u16x8 o;
        o[0] = f2bf(a.x); o[1] = f2bf(a.y); o[2] = f2bf(a.z); o[3] = f2bf(a.w);
        o[4] = f2bf(c.x); o[5] = f2bf(c.y); o[6] = f2bf(c.z); o[7] = f2bf(c.w);
        *(u16x8*)&wl[r * 256 + ((g ^ (r & 31)) * 8)] = o;
    }
    // stage x slab [256 c][128 n] as bf16 (layout unchanged: coalesced writes)
    for (int i = tid; i < 256 * 16; i += 256) {
        int c = i >> 4, oc = i & 15;
        const float* xs = x + ((size_t)b * CCH + c) * NS + n0 + oc * 8;
        float4 a = *(const float4*)xs;
        float4 d = *(const float4*)(xs + 4);
        u16x8 o;
        o[0] = f2bf(a.x); o[1] = f2bf(a.y); o[2] = f2bf(a.z); o[3] = f2bf(a.w);
        o[4] = f2bf(d.x); o[5] = f2bf(d.y); o[6] = f2bf(d.z); o[7] = f2bf(d.w);
        *(u16x8*)&xl[c * 128 + oc * 8] = o;
    }
    __syncthreads();

    const int w = tid >> 6, l = tid & 63;
    const int l31 = l & 31, l5 = l >> 5;

    f32x16 acc[5] = {};
    for (int kh = 0; kh < 16; kh++) {
        // B-frag: lane = token (32w+l31), k = c-range kh*16+l5*8..+8 (transpose reads)
        bhalf8 bf;
#pragma unroll
        for (int e = 0; e < 8; e++)
            bf[e] = (short)xl[(kh * 16 + l5 * 8 + e) * 128 + w * 32 + l31];
#pragma unroll
        for (int rt = 0; rt < 5; rt++) {
            int row = rt * 32 + l31;
            bhalf8 af = *(const bhalf8*)&wl[row * 256 + (((kh * 2 + l5) ^ l31) * 8)];
            acc[rt] = __builtin_amdgcn_mfma_f32_32x32x16_bf16(af, bf, acc[rt], 0, 0, 0);
        }
    }

    // epilogue: C/D row=(r&3)+8*(r>>2)+4*l5, col=token=l31
    const int n = n0 + w * 32 + l31;
#pragma unroll
    for (int rt = 0; rt < 5; rt++) {
        int gr0 = ms * 160 + rt * 32;
        if (gr0 < 64) {            // q (gr0==0) or k (gr0==32): token-major [N][32]
            unsigned short* dst = (gr0 == 0 ? qt : kt) + ((size_t)b * NS + n) * DQ;
            const float* bias = (gr0 == 0 ? bq : bk);
#pragma unroll
            for (int gq = 0; gq < 4; gq++) {
                int m0 = gq * 8 + l5 * 4;
                float4 bs = *(const float4*)(bias + m0);
                ushort4 o;
                o.x = f2bf(acc[rt][4 * gq + 0] + bs.x);
                o.y = f2bf(acc[rt][4 * gq + 1] + bs.y);
                o.z = f2bf(acc[rt][4 * gq + 2] + bs.z);
                o.w = f2bf(acc[rt][4 * gq + 3] + bs.w);
                *(ushort4*)(dst + m0) = o;
            }
        } else {                   // v rows: [C][N]
            int c0 = gr0 - 64;
#pragma unroll
            for (int gq = 0; gq < 4; gq++) {
                int m0 = gq * 8 + l5 * 4;
                float4 bs = *(const float4*)(bv + c0 + m0);
                const float* bse = (const float*)&bs;
#pragma unroll
                for (int e = 0; e < 4; e++)
                    vt[((size_t)b * CCH + c0 + m0 + e) * NS + n] =
                        f2bf(acc[rt][4 * gq + e] + bse[e]);
            }
        }
    }
}

// ============ fused attention: C-split, 2 blocks/CU ==========================
// grid 512 = b(4) x i-tile(64: TI=64 rows) x ch(2: 128 channels). 8 waves.
// Single-buffered V (async global->LDS, issued right after the PV barrier so
// it flies under the next S/exp phase). P via LDS, XOR-swizzled granules.
// No max-subtraction: logits bounded ~|34| << 88 (fp32 exp overflow).
__global__ __launch_bounds__(512, 4) void attn_kernel(
    const unsigned short* __restrict__ qg, const unsigned short* __restrict__ kg,
    const unsigned short* __restrict__ vg, const float* __restrict__ x,
    const float* __restrict__ gamma, float* __restrict__ out)
{
    __shared__ unsigned short vbuf[128][TJ];   // 32 KB, granule-swizzled per row
    __shared__ unsigned short pt[TI][TJ];      // 16 KB, granule-swizzled per row
    __shared__ float dsum[4][TI];
    __shared__ float dinv[TI];

    const int tid = threadIdx.x;
    const int w = tid >> 6, l = tid & 63;
    const int l31 = l & 31, l5 = l >> 5;
    const int ch  = blockIdx.x & 1;
    const int it  = (blockIdx.x >> 1) & 63;
    const int b   = blockIdx.x >> 7;
    const int i0  = it * TI;
    const int ibs = w >> 2, jb = w & 3;        // S-phase tile
    const int ibp = w & 1, cbp = w >> 1;       // PV-phase tile

    const unsigned short* qb = qg + ((size_t)b * NS + i0) * DQ;
    const unsigned short* kb = kg + (size_t)b * NS * DQ;
    const unsigned short* vb = vg + ((size_t)b * CCH + ch * 128) * NS;

    // V staging geometry: inst t covers rows 16w+4t..+3; lane l -> row +(l>>4),
    // phys granule l&15 holds logical granule (l&15)^(row&15).
    const int vr = 16 * w + (l >> 4);

    // loop-invariant Q A-frags
    bhalf8 qa[2];
#pragma unroll
    for (int kh = 0; kh < 2; kh++)
        qa[kh] = *(const bhalf8*)(qb + (size_t)(32 * ibs + l31) * DQ + kh * 16 + l5 * 8);

    f32x16 acc = {};
    float dpart[16] = {};

    // prologue: V tile 0 + K frags tile 0
#pragma unroll
    for (int t = 0; t < 4; t++) {
        int r = vr + 4 * t;
        async_copy16(&vbuf[16 * w + 4 * t][0],
                     vb + (size_t)r * NS + (((l & 15) ^ (r & 15)) * 8));
    }
    bhalf8 kf[2], kfn[2];
#pragma unroll
    for (int kh = 0; kh < 2; kh++)
        kf[kh] = *(const bhalf8*)(kb + (size_t)(32 * jb + l31) * DQ + kh * 16 + l5 * 8);

    for (int jt = 0; jt < NS / TJ; jt++) {
        // S = Q.K^T (one 32x32 tile per wave)
        f32x16 s = {};
        s = __builtin_amdgcn_mfma_f32_32x32x16_bf16(qa[0], kf[0], s, 0, 0, 0);
        s = __builtin_amdgcn_mfma_f32_32x32x16_bf16(qa[1], kf[1], s, 0, 0, 0);

#pragma unroll
        for (int r = 0; r < 16; r++) {
            float p = __expf(s[r]);
            dpart[r] += p;
            int il = 32 * ibs + (r & 3) + 8 * (r >> 2) + 4 * l5;
            int jl = 32 * jb + l31;
            pt[il][(((jl >> 3) ^ (il & 15)) << 3) + (jl & 7)] = f2bf(p);
        }
        __syncthreads();   // B1: pt visible; V asyncs for this jt drained

        // prefetch next K frags (global, overlaps PV)
        if (jt + 1 < NS / TJ) {
#pragma unroll
            for (int kh = 0; kh < 2; kh++)
                kfn[kh] = *(const bhalf8*)(kb + (size_t)((jt + 1) * TJ + 32 * jb + l31) * DQ
                                           + kh * 16 + l5 * 8);
        }

        // PV: wave tile rows 32*ibp.., cols c_local 32*cbp+l31
        const int cl = 32 * cbp + l31;
        const int il = 32 * ibp + l31;
#pragma unroll
        for (int kh = 0; kh < 8; kh++) {
            bhalf8 pa = *(const bhalf8*)&pt[il][(((kh * 2 + l5) ^ (il & 15)) << 3)];
            bhalf8 vf = *(const bhalf8*)&vbuf[cl][(((kh * 2 + l5) ^ (cl & 15)) << 3)];
            acc = __builtin_amdgcn_mfma_f32_32x32x16_bf16(pa, vf, acc, 0, 0, 0);
        }
        __syncthreads();   // B2: vbuf/pt reads complete

        if (jt + 1 < NS / TJ) {
            const unsigned short* vs = vb + (size_t)(jt + 1) * TJ;
#pragma unroll
            for (int t = 0; t < 4; t++) {
                int r = vr + 4 * t;
                async_copy16(&vbuf[16 * w + 4 * t][0],
                             vs + (size_t)r * NS + (((l & 15) ^ (r & 15)) * 8));
            }
            kf[0] = kfn[0]; kf[1] = kfn[1];
        }
    }

    // denominator: reduce over 32 j-lanes, combine 4 jb waves via LDS
#pragma unroll
    for (int m = 16; m >= 1; m >>= 1)
#pragma unroll
        for (int r = 0; r < 16; r++)
            dpart[r] += __shfl_xor(dpart[r], m, 64);
    if (l31 == 0) {
#pragma unroll
        for (int r = 0; r < 16; r++) {
            int il = 32 * ibs + (r & 3) + 8 * (r >> 2) + 4 * l5;
            dsum[jb][il] = dpart[r];
        }
    }
    __syncthreads();
    if (tid < TI)
        dinv[tid] = gamma[0] / (dsum[0][tid] + dsum[1][tid] + dsum[2][tid] + dsum[3][tid]);
    __syncthreads();

    // epilogue: stage normalized tile in LDS (reuse vbuf: 128c x 64i fp32),
    // then coalesced read-add-x-store.
    float* otile = (float*)&vbuf[0][0];
    const int cl = 32 * cbp + l31;
#pragma unroll
    for (int rg = 0; rg < 4; rg++) {
        int ibase = 32 * ibp + 8 * rg + 4 * l5;
        int phys = (ibase >> 2) ^ (cl & 15);
        float4 ov;
        ov.x = acc[4 * rg + 0] * dinv[ibase + 0];
        ov.y = acc[4 * rg + 1] * dinv[ibase + 1];
        ov.z = acc[4 * rg + 2] * dinv[ibase + 2];
        ov.w = acc[4 * rg + 3] * dinv[ibase + 3];
        *(float4*)(otile + cl * 64 + phys * 4) = ov;
    }
    __syncthreads();
#pragma unroll
    for (int ri = 0; ri < 4; ri++) {
        int idx = ri * 512 + tid;
        int cc = idx >> 4, gi = idx & 15;
        float4 vo = *(const float4*)(otile + cc * 64 + ((gi ^ (cc & 15)) << 2));
        const size_t go = ((size_t)b * CCH + ch * 128 + cc) * NS + i0 + gi * 4;
        float4 xr = *(const float4*)(x + go);
        vo.x += xr.x; vo.y += xr.y; vo.z += xr.z; vo.w += xr.w;
        *(float4*)(out + go) = vo;
    }
}

extern "C" void kernel_launch(void* const* d_in, const int* in_sizes, int n_in,
                              void* d_out, int out_size, void* d_ws, size_t ws_size,
                              hipStream_t stream) {
    const float* x     = (const float*)d_in[0];
    const float* wq    = (const float*)d_in[1];
    const float* bq    = (const float*)d_in[2];
    const float* wk    = (const float*)d_in[3];
    const float* bk    = (const float*)d_in[4];
    const float* wv    = (const float*)d_in[5];
    const float* bv    = (const float*)d_in[6];
    const float* gamma = (const float*)d_in[7];
    float* out = (float*)d_out;

    unsigned short* ws = (unsigned short*)d_ws;
    unsigned short* qt = ws;                          // 1 MB
    unsigned short* kt = qt + (size_t)BB * NS * DQ;   // 1 MB
    unsigned short* vt = kt + (size_t)BB * NS * DQ;   // 8 MB

    proj_kernel<<<dim3(256), 256, 0, stream>>>(x, wq, bq, wk, bk, wv, bv, qt, kt, vt);
    attn_kernel<<<dim3(512), 512, 0, stream>>>(qt, kt, vt, x, gamma, out);
}